// Round 9
// baseline (19518.811 us; speedup 1.0000x reference)
//
#include <hip/hip_runtime.h>
#include <math.h>

// Problem constants
#define B_ 256
#define S_ 128
#define F_ 128
#define H_ 512
#define A_ 512
#define C_ 128

// ---------------------------------------------------------------------------
// helpers
// ---------------------------------------------------------------------------
template<bool SC1>
__device__ __forceinline__ float ldf(const float* p)
{
    if constexpr (SC1)
        return __hip_atomic_load(p, __ATOMIC_RELAXED, __HIP_MEMORY_SCOPE_AGENT);
    else
        return *p;
}

__device__ __forceinline__ void stf(float* p, float v)
{
    __hip_atomic_store(p, v, __ATOMIC_RELAXED, __HIP_MEMORY_SCOPE_AGENT);
}

__device__ __forceinline__ void spin_flag(const int* f, int target)
{
    while (__hip_atomic_load(f, __ATOMIC_RELAXED, __HIP_MEMORY_SCOPE_AGENT) < target)
        __builtin_amdgcn_s_sleep(1);
}

// deep-prefetch k-major dot: 32-chunk double buffer (64 VGPR window).
// acc slots 0..3 = r0,r1,z0,z1 ; acc[NH],acc[NH+1] = n0,n1 part.
template<int NH, bool SC1>
__device__ __forceinline__ void acc_chunks(const float* __restrict__ src,
                                           const float* __restrict__ W6k,
                                           int nk, int b, float* __restrict__ acc)
{
    float a0[32], a1[32];
#pragma unroll
    for (int j = 0; j < 32; ++j) a0[j] = ldf<SC1>(src + (size_t)j * B_ + b);
    for (int kc = 0; kc < nk; kc += 32) {
        if (kc + 32 < nk) {
#pragma unroll
            for (int j = 0; j < 32; ++j)
                a1[j] = ldf<SC1>(src + (size_t)(kc + 32 + j) * B_ + b);
        }
        const float* Wr = W6k + (size_t)kc * 6;
#pragma unroll
        for (int j = 0; j < 32; ++j) {
            float av = a0[j];
            acc[0]    = fmaf(av, Wr[j * 6 + 0], acc[0]);
            acc[1]    = fmaf(av, Wr[j * 6 + 1], acc[1]);
            acc[2]    = fmaf(av, Wr[j * 6 + 2], acc[2]);
            acc[3]    = fmaf(av, Wr[j * 6 + 3], acc[3]);
            acc[NH]   = fmaf(av, Wr[j * 6 + 4], acc[NH]);
            acc[NH+1] = fmaf(av, Wr[j * 6 + 5], acc[NH + 1]);
        }
#pragma unroll
        for (int j = 0; j < 32; ++j) a0[j] = a1[j];
    }
}

// ---------------------------------------------------------------------------
// prep kernels
// ---------------------------------------------------------------------------
__global__ __launch_bounds__(256)
void transpose_x(const float* __restrict__ x, float* __restrict__ xT)
{
    const int t = blockIdx.x >> 2;
    const int f0 = (blockIdx.x & 3) * 32;
    const int b = threadIdx.x;
#pragma unroll 4
    for (int ff = 0; ff < 32; ++ff) {
        int f = f0 + ff;
        xT[(size_t)t * (F_ * B_) + (size_t)f * B_ + b] =
            x[(size_t)b * (S_ * F_) + (size_t)t * F_ + f];
    }
}

// W6[up][k][6], up=unit-pair. Optionally zero zbuf[0..zn).
__global__ __launch_bounds__(256)
void prep_w6(const float* __restrict__ Wih, const float* __restrict__ Whh,
             float* __restrict__ W6, float* __restrict__ zbuf, int zn)
{
    int id = blockIdx.x * 256 + threadIdx.x;
    if (zbuf && id < zn) zbuf[id] = 0.f;
    if (id >= 256 * 640 * 6) return;
    int up = id / 3840;
    int rem = id - up * 3840;
    int k = rem / 6, g = rem - k * 6;
    int row = (g >> 1) * H_ + up * 2 + (g & 1);
    float val;
    if (k < F_) val = Wih[(size_t)row * F_ + k];
    else        val = Whh[(size_t)row * H_ + (k - F_)];
    W6[id] = val;
}

// bias4[u] = {br, bz, bin, bhn}; zero h0T; zero flag arrays
__global__ __launch_bounds__(256)
void prep_bias(const float* __restrict__ ebih, const float* __restrict__ ebhh,
               const float* __restrict__ dbih, const float* __restrict__ dbhh,
               float* __restrict__ bias4e, float* __restrict__ bias4d,
               float* __restrict__ h0T, int* __restrict__ eflags,
               int* __restrict__ dflags)
{
    int id = blockIdx.x * 256 + threadIdx.x;
    if (id < H_ * B_) h0T[id] = 0.f;
    if (id < 256 * 32) { eflags[id] = 0; dflags[id] = 0; }
    if (id < H_) {
        bias4e[id * 4 + 0] = ebih[id] + ebhh[id];
        bias4e[id * 4 + 1] = ebih[H_ + id] + ebhh[H_ + id];
        bias4e[id * 4 + 2] = ebih[2 * H_ + id];
        bias4e[id * 4 + 3] = ebhh[2 * H_ + id];
        bias4d[id * 4 + 0] = dbih[id] + dbhh[id];
        bias4d[id * 4 + 1] = dbih[H_ + id] + dbhh[H_ + id];
        bias4d[id * 4 + 2] = dbih[2 * H_ + id];
        bias4d[id * 4 + 3] = dbhh[2 * H_ + id];
    }
}

// ---------------------------------------------------------------------------
// PERSISTENT encoder. 256 blocks x 512 thr. Block = (jb: 8 units) x (bt: 64 b).
// Wave w: kw=w>>2 (k-half), uq=w&3 (unit-pair within jb). W6 slice = jb*4+uq.
// h published sc1 into virgin slice encT[t]; reads normal cached.
// ---------------------------------------------------------------------------
__global__ __launch_bounds__(512)
void enc_persist(const float* __restrict__ xT,     // [S][F][B]
                 const float* __restrict__ W6,     // [256][640][6]
                 const float* __restrict__ bias4,  // [512][4]
                 const float* __restrict__ h0T,    // [H][B] zeros
                 float* __restrict__ encT,         // [S][H][B]
                 int* __restrict__ eflags)         // [256*32]
{
    __shared__ float accL[4][64][6];
    const int tid = threadIdx.x;
    const int lane = tid & 63;
    const int w = tid >> 6;
    const int kw = w >> 2;
    const int uq = w & 3;
    const int jb = blockIdx.x >> 2;
    const int bt = blockIdx.x & 3;
    const int b = bt * 64 + lane;
    const int up = jb * 4 + uq;
    const float* Wb = W6 + (size_t)up * 3840;
    const int u0 = up * 2, u1 = u0 + 1;
    const float4 bb0 = *(const float4*)(bias4 + u0 * 4);
    const float4 bb1 = *(const float4*)(bias4 + u1 * 4);

    for (int t = 0; t < S_; ++t) {
        const float* inT = xT + (size_t)t * (F_ * B_);
        const float* hin = (t == 0) ? h0T : encT + (size_t)(t - 1) * (H_ * B_);
        float* hout = encT + (size_t)t * (H_ * B_);

        float acc[8];
#pragma unroll
        for (int g = 0; g < 8; ++g) acc[g] = 0.f;

        // x-part first (independent of h) hides the wait below
        if (kw == 0) acc_chunks<4, false>(inT, Wb, F_, b, acc);

        if (t > 0 && tid < 256) spin_flag(&eflags[tid * 32], t);
        __syncthreads();

        float hold0 = 0.f, hold1 = 0.f;
        if (kw == 0) {
            hold0 = hin[(size_t)u0 * B_ + b];
            hold1 = hin[(size_t)u1 * B_ + b];
            acc_chunks<6, false>(hin, Wb + F_ * 6, 192, b, acc);
        } else {
            acc_chunks<6, false>(hin + (size_t)192 * B_, Wb + 320 * 6, 320, b, acc);
        }

        if (kw == 1) {
            accL[uq][lane][0] = acc[0]; accL[uq][lane][1] = acc[1];
            accL[uq][lane][2] = acc[2]; accL[uq][lane][3] = acc[3];
            accL[uq][lane][4] = acc[6]; accL[uq][lane][5] = acc[7];
        }
        __syncthreads();
        if (kw == 0) {
            float rr0 = 1.f / (1.f + expf(-(acc[0] + accL[uq][lane][0] + bb0.x)));
            float rr1 = 1.f / (1.f + expf(-(acc[1] + accL[uq][lane][1] + bb1.x)));
            float zz0 = 1.f / (1.f + expf(-(acc[2] + accL[uq][lane][2] + bb0.y)));
            float zz1 = 1.f / (1.f + expf(-(acc[3] + accL[uq][lane][3] + bb1.y)));
            float hn0 = acc[6] + accL[uq][lane][4] + bb0.w;
            float hn1 = acc[7] + accL[uq][lane][5] + bb1.w;
            float nn0 = tanhf(acc[4] + bb0.z + rr0 * hn0);
            float nn1 = tanhf(acc[5] + bb1.z + rr1 * hn1);
            stf(&hout[(size_t)u0 * B_ + b], (1.f - zz0) * nn0 + zz0 * hold0);
            stf(&hout[(size_t)u1 * B_ + b], (1.f - zz1) * nn1 + zz1 * hold1);
        }
        asm volatile("s_waitcnt vmcnt(0)" ::: "memory");
        __syncthreads();
        if (tid == 0) {
            __hip_atomic_store(&eflags[blockIdx.x * 32], t + 1,
                               __ATOMIC_RELAXED, __HIP_MEMORY_SCOPE_AGENT);
        }
    }
}

// ---------------------------------------------------------------------------
// PERSISTENT decoder. 256 blocks x 512 thr, 128 steps, 3 phases/step.
// Epochs: GRU publish = 3s+1, hw2 publish = 3s+2, dec_in publish = 3s+3.
// All step-rewritten buffers (h, dec_in, hw2) read via sc1.
// ---------------------------------------------------------------------------
__global__ __launch_bounds__(512)
void dec_persist(const float* __restrict__ x,      // [B][S][F] original
                 const int*   __restrict__ y,      // [B][C]
                 const float* __restrict__ W6,     // [256][640][6]
                 const float* __restrict__ bias4,  // [512][4]
                 const float* __restrict__ w2,     // [A][H] original
                 const float* __restrict__ v,      // [A]
                 const float* __restrict__ proj,   // [B][S][A]
                 const float* __restrict__ h_init, // [H][B] = encT[127]
                 float* __restrict__ hT0, float* __restrict__ hT1,
                 float* __restrict__ dec_inT,      // [F][B]
                 float* __restrict__ hw2,          // [B][A]
                 float* __restrict__ nlogp, float* __restrict__ preds,
                 int* __restrict__ dflags)         // [256*32]
{
    __shared__ float accL[4][64][6];
    __shared__ float accP[256][8];
    __shared__ float sq[512];
    __shared__ float sScore[S_], sProb[S_];
    __shared__ int sPred;

    const int tid = threadIdx.x;
    const int lane = tid & 63;
    const int w = tid >> 6;
    const int kw = w >> 2;
    const int uq = w & 3;
    const int jb = blockIdx.x >> 2;
    const int bt = blockIdx.x & 3;
    const int b = bt * 64 + lane;
    const int up = jb * 4 + uq;
    const float* Wb = W6 + (size_t)up * 3840;
    const int u0 = up * 2, u1 = u0 + 1;
    const float4 bb0 = *(const float4*)(bias4 + u0 * 4);
    const float4 bb1 = *(const float4*)(bias4 + u1 * 4);
    const float4 v0r = *(const float4*)(v + lane * 8);
    const float4 v1r = *(const float4*)(v + lane * 8 + 4);
    const int bid = blockIdx.x;

    for (int st = 0; st < C_; ++st) {
        const float* hin = (st == 0) ? h_init : ((st & 1) ? hT0 : hT1);
        float* hout = (st & 1) ? hT1 : hT0;

        // ---------------- phase 1: GRU ----------------
        {
            float acc[8];
#pragma unroll
            for (int g = 0; g < 8; ++g) acc[g] = 0.f;

            float hold0 = 0.f, hold1 = 0.f;
            // h-part first: h(st-1) already published before this block's last wait
            if (kw == 0) {
                hold0 = ldf<true>(hin + (size_t)u0 * B_ + b);
                hold1 = ldf<true>(hin + (size_t)u1 * B_ + b);
                acc_chunks<6, true>(hin, Wb + F_ * 6, 192, b, acc);
            } else {
                acc_chunks<6, true>(hin + (size_t)192 * B_, Wb + 320 * 6, 320, b, acc);
            }

            // wait for dec_in(st) (published by phase 3 of st-1)
            if (st > 0 && tid < 256) spin_flag(&dflags[tid * 32], 3 * st);
            __syncthreads();

            if (kw == 0) acc_chunks<4, true>(dec_inT, Wb, F_, b, acc);

            if (kw == 1) {
                accL[uq][lane][0] = acc[0]; accL[uq][lane][1] = acc[1];
                accL[uq][lane][2] = acc[2]; accL[uq][lane][3] = acc[3];
                accL[uq][lane][4] = acc[6]; accL[uq][lane][5] = acc[7];
            }
            __syncthreads();
            if (kw == 0) {
                float rr0 = 1.f / (1.f + expf(-(acc[0] + accL[uq][lane][0] + bb0.x)));
                float rr1 = 1.f / (1.f + expf(-(acc[1] + accL[uq][lane][1] + bb1.x)));
                float zz0 = 1.f / (1.f + expf(-(acc[2] + accL[uq][lane][2] + bb0.y)));
                float zz1 = 1.f / (1.f + expf(-(acc[3] + accL[uq][lane][3] + bb1.y)));
                float hn0 = acc[6] + accL[uq][lane][4] + bb0.w;
                float hn1 = acc[7] + accL[uq][lane][5] + bb1.w;
                float nn0 = tanhf(acc[4] + bb0.z + rr0 * hn0);
                float nn1 = tanhf(acc[5] + bb1.z + rr1 * hn1);
                stf(&hout[(size_t)u0 * B_ + b], (1.f - zz0) * nn0 + zz0 * hold0);
                stf(&hout[(size_t)u1 * B_ + b], (1.f - zz1) * nn1 + zz1 * hold1);
            }
            asm volatile("s_waitcnt vmcnt(0)" ::: "memory");
            __syncthreads();
            if (tid == 0)
                __hip_atomic_store(&dflags[bid * 32], 3 * st + 1,
                                   __ATOMIC_RELAXED, __HIP_MEMORY_SCOPE_AGENT);
        }

        // ---------------- phase 2: hw2 slice (blocks 0..63) ----------------
        if (tid < 256) spin_flag(&dflags[tid * 32], 3 * st + 1);
        __syncthreads();
        if (bid < 64) {
            const int a0 = bid * 8;
            const int pb = tid & 255;
            const int kh = tid >> 8;
            const float* hsrc = hout + (size_t)(kh * 256) * B_;
            const float* w2b = w2 + (size_t)a0 * H_ + kh * 256;
            float pacc[8];
#pragma unroll
            for (int j = 0; j < 8; ++j) pacc[j] = 0.f;
            {
                float c0[32], c1[32];
#pragma unroll
                for (int j = 0; j < 32; ++j)
                    c0[j] = ldf<true>(hsrc + (size_t)j * B_ + pb);
                for (int kc = 0; kc < 256; kc += 32) {
                    if (kc + 32 < 256) {
#pragma unroll
                        for (int j = 0; j < 32; ++j)
                            c1[j] = ldf<true>(hsrc + (size_t)(kc + 32 + j) * B_ + pb);
                    }
#pragma unroll
                    for (int j = 0; j < 32; ++j) {
                        float av = c0[j];
#pragma unroll
                        for (int jj = 0; jj < 8; ++jj)
                            pacc[jj] = fmaf(av, w2b[(size_t)jj * H_ + kc + j], pacc[jj]);
                    }
#pragma unroll
                    for (int j = 0; j < 32; ++j) c0[j] = c1[j];
                }
            }
            if (kh == 1) {
#pragma unroll
                for (int j = 0; j < 8; ++j) accP[pb][j] = pacc[j];
            }
            __syncthreads();
            if (kh == 0) {
#pragma unroll
                for (int j = 0; j < 8; ++j)
                    stf(&hw2[(size_t)pb * A_ + a0 + j], pacc[j] + accP[pb][j]);
            }
        }
        asm volatile("s_waitcnt vmcnt(0)" ::: "memory");
        __syncthreads();
        if (tid == 0)
            __hip_atomic_store(&dflags[bid * 32], 3 * st + 2,
                               __ATOMIC_RELAXED, __HIP_MEMORY_SCOPE_AGENT);

        // ---------------- phase 3: attention (block = batch bb) ----------------
        if (tid < 256) spin_flag(&dflags[tid * 32], 3 * st + 2);
        __syncthreads();
        {
            const int bb = bid;
            sq[tid] = ldf<true>(&hw2[(size_t)bb * A_ + tid]);
            __syncthreads();

            float4 q0 = *(const float4*)&sq[lane * 8];
            float4 q1 = *(const float4*)&sq[lane * 8 + 4];
            const float* epb = proj + (size_t)bb * (S_ * A_);
            for (int si = 0; si < 16; ++si) {
                int ss = si * 8 + w;
                const float* row = epb + (size_t)ss * A_ + lane * 8;
                float4 p0 = *(const float4*)(row);
                float4 p1 = *(const float4*)(row + 4);
                float acc = fmaxf(p0.x + q0.x, 0.f) * v0r.x
                          + fmaxf(p0.y + q0.y, 0.f) * v0r.y
                          + fmaxf(p0.z + q0.z, 0.f) * v0r.z
                          + fmaxf(p0.w + q0.w, 0.f) * v0r.w
                          + fmaxf(p1.x + q1.x, 0.f) * v1r.x
                          + fmaxf(p1.y + q1.y, 0.f) * v1r.y
                          + fmaxf(p1.z + q1.z, 0.f) * v1r.z
                          + fmaxf(p1.w + q1.w, 0.f) * v1r.w;
#pragma unroll
                for (int off = 32; off; off >>= 1) acc += __shfl_down(acc, off);
                if (lane == 0) sScore[ss] = acc;
            }
            __syncthreads();

            if (tid < 64) {
                float s0v = sScore[tid], s1v = sScore[tid + 64];
                float m = fmaxf(s0v, s1v);
#pragma unroll
                for (int off = 32; off; off >>= 1) m = fmaxf(m, __shfl_xor(m, off));
                float e0 = expf(s0v - m), e1 = expf(s1v - m);
                float se = e0 + e1;
#pragma unroll
                for (int off = 32; off; off >>= 1) se += __shfl_xor(se, off);
                float p0 = e0 / se, p1 = e1 / se;
                sProb[tid] = p0; sProb[tid + 64] = p1;
                float pm = fmaxf(p0, p1);
#pragma unroll
                for (int off = 32; off; off >>= 1) pm = fmaxf(pm, __shfl_xor(pm, off));
                float t0 = expf(p0 - pm), t1 = expf(p1 - pm);
                float T = t0 + t1;
#pragma unroll
                for (int off = 32; off; off >>= 1) T += __shfl_xor(T, off);
                float bv = p0; int bi2 = tid;
                if (p1 > bv) { bv = p1; bi2 = tid + 64; }
#pragma unroll
                for (int off = 32; off; off >>= 1) {
                    float ov = __shfl_xor(bv, off);
                    int oi = __shfl_xor(bi2, off);
                    if (ov > bv || (ov == bv && oi < bi2)) { bv = ov; bi2 = oi; }
                }
                if (tid == 0) {
                    sPred = bi2;
                    int yy = y[(size_t)bb * C_ + st];
                    float py = sProb[yy];
                    nlogp[(size_t)st * B_ + bb] = -(py - pm - logf(T));
                    preds[(size_t)bb * C_ + st] = (float)bi2;
                }
            }
            __syncthreads();

            const int pred = sPred;
            if (tid < F_) {
                stf(&dec_inT[(size_t)tid * B_ + bb],
                    x[((size_t)bb * S_ + pred) * F_ + tid]);
            }
        }
        asm volatile("s_waitcnt vmcnt(0)" ::: "memory");
        __syncthreads();
        if (tid == 0)
            __hip_atomic_store(&dflags[bid * 32], 3 * st + 3,
                               __ATOMIC_RELAXED, __HIP_MEMORY_SCOPE_AGENT);
    }
}

// ---------------------------------------------------------------------------
// proj[b][s][a] = sum_j encT[s][j][b] * w1[a][j]
// ---------------------------------------------------------------------------
__global__ __launch_bounds__(256)
void proj_gemm(const float* __restrict__ encT, const float* __restrict__ w1,
               float* __restrict__ proj)
{
    __shared__ float sA[32][128];
    __shared__ float sB[32][128];
    const int tid = threadIdx.x;
    const int s = blockIdx.z;
    const int b0 = blockIdx.y * 128;
    const int a0 = blockIdx.x * 128;
    const int tx = tid & 15, ty = tid >> 4;

    float acc[8][8];
#pragma unroll
    for (int i = 0; i < 8; ++i)
#pragma unroll
        for (int j = 0; j < 8; ++j) acc[i][j] = 0.f;

    const float* Abase = encT + (size_t)s * (H_ * B_) + b0;
    for (int kc = 0; kc < H_; kc += 32) {
#pragma unroll
        for (int p = 0; p < 16; ++p) {
            int idx = tid + p * 256;
            int kj = idx >> 7, bbb = idx & 127;
            sA[kj][bbb] = Abase[(size_t)(kc + kj) * B_ + bbb];
        }
#pragma unroll
        for (int p = 0; p < 16; ++p) {
            int idx = tid + p * 256;
            int aa = idx >> 5, kj = idx & 31;
            sB[kj][aa] = w1[(size_t)(a0 + aa) * H_ + kc + kj];
        }
        __syncthreads();
#pragma unroll
        for (int kj = 0; kj < 32; ++kj) {
            float4 af0 = *(const float4*)&sA[kj][ty * 8];
            float4 af1 = *(const float4*)&sA[kj][ty * 8 + 4];
            float4 bf0 = *(const float4*)&sB[kj][tx * 8];
            float4 bf1 = *(const float4*)&sB[kj][tx * 8 + 4];
            float am[8] = {af0.x, af0.y, af0.z, af0.w, af1.x, af1.y, af1.z, af1.w};
            float bn[8] = {bf0.x, bf0.y, bf0.z, bf0.w, bf1.x, bf1.y, bf1.z, bf1.w};
#pragma unroll
            for (int i = 0; i < 8; ++i)
#pragma unroll
                for (int j = 0; j < 8; ++j)
                    acc[i][j] = fmaf(am[i], bn[j], acc[i][j]);
        }
        __syncthreads();
    }
#pragma unroll
    for (int i = 0; i < 8; ++i) {
        float* dst = proj + ((size_t)(b0 + ty * 8 + i) * S_ + s) * A_ + a0 + tx * 8;
        *(float4*)(dst) = make_float4(acc[i][0], acc[i][1], acc[i][2], acc[i][3]);
        *(float4*)(dst + 4) = make_float4(acc[i][4], acc[i][5], acc[i][6], acc[i][7]);
    }
}

__global__ void final_loss(const float* __restrict__ nlogp, float* __restrict__ out)
{
    __shared__ float part[C_];
    const int i = threadIdx.x; // 128
    float s = 0.f;
    for (int b = 0; b < B_; ++b) s += nlogp[(size_t)i * B_ + b];
    part[i] = s / (float)B_;
    __syncthreads();
    if (i == 0) {
        float t = 0.f;
        for (int k = 0; k < C_; ++k) t += part[k];
        out[0] = t / (float)B_ / (float)C_;
    }
}

extern "C" void kernel_launch(void* const* d_in, const int* in_sizes, int n_in,
                              void* d_out, int out_size, void* d_ws, size_t ws_size,
                              hipStream_t stream)
{
    (void)in_sizes; (void)n_in; (void)out_size; (void)ws_size;
    const float* x    = (const float*)d_in[0];
    const int*   y    = (const int*)d_in[1];
    const float* eWih = (const float*)d_in[2];
    const float* eWhh = (const float*)d_in[3];
    const float* ebih = (const float*)d_in[4];
    const float* ebhh = (const float*)d_in[5];
    const float* dWih = (const float*)d_in[6];
    const float* dWhh = (const float*)d_in[7];
    const float* dbih = (const float*)d_in[8];
    const float* dbhh = (const float*)d_in[9];
    const float* w1   = (const float*)d_in[10];
    const float* w2   = (const float*)d_in[11];
    const float* v    = (const float*)d_in[12];
    float* out = (float*)d_out;

    float* ws = (float*)d_ws;
    // Region A: encT [128][512][256] = 16,777,216 floats.
    // After proj_gemm, slices 0..126 are dead; decoder scratch lives there.
    float* encT    = ws;
    float* W6d     = ws;                    // 983,040
    float* hT0     = ws + 983040;           // 131,072
    float* hT1     = ws + 1114112;          // 131,072
    float* dec_inT = ws + 1245184;          // 32,768
    float* nlogp   = ws + 1277952;          // 32,768
    float* hw2     = ws + 1310720;          // 131,072  (ends 1,441,792)
    float* encT127 = ws + 16646144;         // encoder final h (stays live)
    // Region B: proj. Before proj written: xT, W6e, h0T.
    float* projB   = ws + 16777216;
    float* xT      = projB;                 // 4,194,304
    float* W6e     = projB + 4194304;       // 983,040
    float* h0T     = projB + 5177344;       // 131,072
    // Region C
    float* bias4e  = ws + 33554432;
    float* bias4d  = bias4e + 2048;
    int*   eflags  = (int*)(bias4d + 2048);   // 256*32 ints
    int*   dflags  = eflags + 256 * 32;       // 256*32 ints

    // ---- prep ----
    prep_bias<<<dim3(512), 256, 0, stream>>>(ebih, ebhh, dbih, dbhh,
                                             bias4e, bias4d, h0T, eflags, dflags);
    transpose_x<<<dim3(512), 256, 0, stream>>>(x, xT);
    prep_w6<<<dim3(3840), 256, 0, stream>>>(eWih, eWhh, W6e, (float*)nullptr, 0);

    // ---- encoder: ONE persistent kernel ----
    {
        void* a[] = { (void*)&xT, (void*)&W6e, (void*)&bias4e, (void*)&h0T,
                      (void*)&encT, (void*)&eflags };
        hipLaunchCooperativeKernel((const void*)enc_persist,
                                   dim3(256), dim3(512), a, 0, stream);
    }

    // ---- proj ----
    proj_gemm<<<dim3(4, 2, 128), 256, 0, stream>>>(encT, w1, projB);

    // ---- decoder prep: pack W6d into dead encT slices + zero dec_inT ----
    prep_w6<<<dim3(3840), 256, 0, stream>>>(dWih, dWhh, W6d, dec_inT, F_ * B_);

    // ---- decoder: ONE persistent kernel ----
    {
        void* a[] = { (void*)&x, (void*)&y, (void*)&W6d, (void*)&bias4d,
                      (void*)&w2, (void*)&v, (void*)&projB, (void*)&encT127,
                      (void*)&hT0, (void*)&hT1, (void*)&dec_inT, (void*)&hw2,
                      (void*)&nlogp, (void*)&out, (void*)&dflags };
        hipLaunchCooperativeKernel((const void*)dec_persist,
                                   dim3(256), dim3(512), a, 0, stream);
    }

    final_loss<<<dim3(1), 128, 0, stream>>>(nlogp, out + (size_t)B_ * C_);
}

// Round 10
// 12465.201 us; speedup vs baseline: 1.5659x; 1.5659x over previous
//
#include <hip/hip_runtime.h>
#include <math.h>

// Problem constants
#define B_ 256
#define S_ 128
#define F_ 128
#define H_ 512
#define A_ 512
#define C_ 128
#define HSLICE (H_ * B_)   // 131072 floats per h slice

#define DOT4(va, vb) ((va).x*(vb).x + (va).y*(vb).y + (va).z*(vb).z + (va).w*(vb).w)

// ---------------------------------------------------------------------------
// coherence helpers: sc1 publish stores, sc1 scalar loads (tiny paths only)
// ---------------------------------------------------------------------------
__device__ __forceinline__ void stf(float* p, float v) {
    __hip_atomic_store(p, v, __ATOMIC_RELAXED, __HIP_MEMORY_SCOPE_AGENT);
}
__device__ __forceinline__ float ldf_sc(const float* p) {
    return __hip_atomic_load(p, __ATOMIC_RELAXED, __HIP_MEMORY_SCOPE_AGENT);
}

// own-slot epoch barrier over a 64-block group; caller __syncthreads() after
__device__ __forceinline__ void group_wait(const int* __restrict__ flags,
                                           int gbase, int tid, int target)
{
    if (tid < 64) {
        while (true) {
            int vq = __hip_atomic_load(&flags[(gbase + tid) * 32],
                                       __ATOMIC_RELAXED,
                                       __HIP_MEMORY_SCOPE_AGENT);
            if (__all(vq >= target)) break;
            __builtin_amdgcn_s_sleep(2);
        }
    }
}

// ---------------------------------------------------------------------------
// deep-prefetch k-major dot (cached loads): 32-float double-buffer window.
// acc slots 0..3 = r0,r1,z0,z1 ; acc[NH],acc[NH+1] = n0,n1 partial.
// ---------------------------------------------------------------------------
template<int NH>
__device__ __forceinline__ void acc_chunks(const float* __restrict__ src,
                                           const float* __restrict__ W6k,
                                           int nk, int b, float* __restrict__ acc)
{
    float a0[32], a1[32];
#pragma unroll
    for (int j = 0; j < 32; ++j) a0[j] = src[(size_t)j * B_ + b];
    for (int kc = 0; kc < nk; kc += 32) {
        if (kc + 32 < nk) {
#pragma unroll
            for (int j = 0; j < 32; ++j)
                a1[j] = src[(size_t)(kc + 32 + j) * B_ + b];
        }
        const float* Wr = W6k + (size_t)kc * 6;
#pragma unroll
        for (int j = 0; j < 32; ++j) {
            float av = a0[j];
            acc[0]    = fmaf(av, Wr[j * 6 + 0], acc[0]);
            acc[1]    = fmaf(av, Wr[j * 6 + 1], acc[1]);
            acc[2]    = fmaf(av, Wr[j * 6 + 2], acc[2]);
            acc[3]    = fmaf(av, Wr[j * 6 + 3], acc[3]);
            acc[NH]   = fmaf(av, Wr[j * 6 + 4], acc[NH]);
            acc[NH+1] = fmaf(av, Wr[j * 6 + 5], acc[NH + 1]);
        }
#pragma unroll
        for (int j = 0; j < 32; ++j) a0[j] = a1[j];
    }
}

// per-lane x-row (128 k, contiguous) against W6 x-part; acc n -> slots 4,5
__device__ __forceinline__ void acc_xrow(const float4* __restrict__ xr,
                                         const float* __restrict__ W6k,
                                         float* __restrict__ acc)
{
    float4 c0[8], c1[8];
#pragma unroll
    for (int j = 0; j < 8; ++j) c0[j] = xr[j];
    for (int q = 0; q < 32; q += 8) {
        if (q + 8 < 32) {
#pragma unroll
            for (int j = 0; j < 8; ++j) c1[j] = xr[q + 8 + j];
        }
#pragma unroll
        for (int j = 0; j < 8; ++j) {
            const float* Wr = W6k + (size_t)((q + j) * 4) * 6;
            float e0 = c0[j].x, e1 = c0[j].y, e2 = c0[j].z, e3 = c0[j].w;
#pragma unroll
            for (int t2 = 0; t2 < 4; ++t2) {
                float av = (t2 == 0) ? e0 : (t2 == 1) ? e1 : (t2 == 2) ? e2 : e3;
                acc[0] = fmaf(av, Wr[t2 * 6 + 0], acc[0]);
                acc[1] = fmaf(av, Wr[t2 * 6 + 1], acc[1]);
                acc[2] = fmaf(av, Wr[t2 * 6 + 2], acc[2]);
                acc[3] = fmaf(av, Wr[t2 * 6 + 3], acc[3]);
                acc[4] = fmaf(av, Wr[t2 * 6 + 4], acc[4]);
                acc[5] = fmaf(av, Wr[t2 * 6 + 5], acc[5]);
            }
        }
#pragma unroll
        for (int j = 0; j < 8; ++j) c0[j] = c1[j];
    }
}

// ---------------------------------------------------------------------------
// prep kernels
// ---------------------------------------------------------------------------
__global__ __launch_bounds__(256)
void transpose_x(const float* __restrict__ x, float* __restrict__ xT)
{
    const int t = blockIdx.x >> 2;
    const int f0 = (blockIdx.x & 3) * 32;
    const int b = threadIdx.x;
#pragma unroll 4
    for (int ff = 0; ff < 32; ++ff) {
        int f = f0 + ff;
        xT[(size_t)t * (F_ * B_) + (size_t)f * B_ + b] =
            x[(size_t)b * (S_ * F_) + (size_t)t * F_ + f];
    }
}

// W6[up][k][6]; optional copy csrc->cdst of cn floats (for h_init -> ring[0])
__global__ __launch_bounds__(256)
void prep_w6(const float* __restrict__ Wih, const float* __restrict__ Whh,
             float* __restrict__ W6, const float* __restrict__ csrc,
             float* __restrict__ cdst, int cn)
{
    int id = blockIdx.x * 256 + threadIdx.x;
    if (csrc && id < cn) cdst[id] = csrc[id];
    if (id >= 256 * 640 * 6) return;
    int up = id / 3840;
    int rem = id - up * 3840;
    int k = rem / 6, g = rem - k * 6;
    int row = (g >> 1) * H_ + up * 2 + (g & 1);
    float val;
    if (k < F_) val = Wih[(size_t)row * F_ + k];
    else        val = Whh[(size_t)row * H_ + (k - F_)];
    W6[id] = val;
}

// w2q[k4][a] = float4{ w2[a][4k4 .. 4k4+3] }
__global__ __launch_bounds__(256)
void prep_w2q(const float* __restrict__ w2, float4* __restrict__ w2q)
{
    int id = blockIdx.x * 256 + threadIdx.x;
    if (id < 128 * 512) {
        int k4 = id >> 9, a = id & 511;
        const float* s = w2 + (size_t)a * H_ + k4 * 4;
        w2q[id] = make_float4(s[0], s[1], s[2], s[3]);
    }
}

// biases; zero h0T and both flag arrays
__global__ __launch_bounds__(256)
void prep_bias(const float* __restrict__ ebih, const float* __restrict__ ebhh,
               const float* __restrict__ dbih, const float* __restrict__ dbhh,
               float* __restrict__ bias4e, float* __restrict__ bias4d,
               float* __restrict__ h0T, int* __restrict__ eflags,
               int* __restrict__ dflags)
{
    int id = blockIdx.x * 256 + threadIdx.x;
    if (id < H_ * B_) h0T[id] = 0.f;
    if (id < 256 * 32) { eflags[id] = 0; dflags[id] = 0; }
    if (id < H_) {
        bias4e[id * 4 + 0] = ebih[id] + ebhh[id];
        bias4e[id * 4 + 1] = ebih[H_ + id] + ebhh[H_ + id];
        bias4e[id * 4 + 2] = ebih[2 * H_ + id];
        bias4e[id * 4 + 3] = ebhh[2 * H_ + id];
        bias4d[id * 4 + 0] = dbih[id] + dbhh[id];
        bias4d[id * 4 + 1] = dbih[H_ + id] + dbhh[H_ + id];
        bias4d[id * 4 + 2] = dbih[2 * H_ + id];
        bias4d[id * 4 + 3] = dbhh[2 * H_ + id];
    }
}

// ---------------------------------------------------------------------------
// PERSISTENT encoder. bid = bt*64 + jb. Block = 8 units (jb) x 64 batch (bt).
// Waves: kw = w>>2 (k-half), uq = w&3 (unit-pair). Group-64 barrier per bt.
// Cached reads of virgin encT slices; sc1 publish stores.
// ---------------------------------------------------------------------------
__global__ __launch_bounds__(512)
void enc_persist(const float* __restrict__ xT,     // [S][F][B]
                 const float* __restrict__ W6,     // [256][640][6]
                 const float* __restrict__ bias4,  // [512][4]
                 const float* __restrict__ h0T,    // [H][B] zeros
                 float* __restrict__ encT,         // [S][H][B]
                 int* __restrict__ eflags)         // [256*32]
{
    __shared__ float accL[4][64][6];
    const int tid = threadIdx.x;
    const int lane = tid & 63;
    const int w = tid >> 6;
    const int kw = w >> 2;
    const int uq = w & 3;
    const int bid = blockIdx.x;
    const int jb = bid & 63;
    const int bt = bid >> 6;
    const int gbase = bt * 64;
    const int b = bt * 64 + lane;
    const int up = jb * 4 + uq;
    const float* Wb = W6 + (size_t)up * 3840;
    const int u0 = up * 2, u1 = u0 + 1;
    const float4 bb0 = *(const float4*)(bias4 + u0 * 4);
    const float4 bb1 = *(const float4*)(bias4 + u1 * 4);

    for (int t = 0; t < S_; ++t) {
        const float* inT = xT + (size_t)t * (F_ * B_);
        const float* hin = (t == 0) ? h0T : encT + (size_t)(t - 1) * HSLICE;
        float* hout = encT + (size_t)t * HSLICE;

        float acc[8];
#pragma unroll
        for (int g = 0; g < 8; ++g) acc[g] = 0.f;

        // x-part first (independent of h) hides the wait
        if (kw == 0) acc_chunks<4>(inT, Wb, F_, b, acc);

        if (t > 0) group_wait(eflags, gbase, tid, t);
        __syncthreads();

        float hold0 = 0.f, hold1 = 0.f;
        if (kw == 0) {
            hold0 = hin[(size_t)u0 * B_ + b];
            hold1 = hin[(size_t)u1 * B_ + b];
            acc_chunks<6>(hin, Wb + F_ * 6, 192, b, acc);
        } else {
            acc_chunks<6>(hin + (size_t)192 * B_, Wb + 320 * 6, 320, b, acc);
        }

        if (kw == 1) {
            accL[uq][lane][0] = acc[0]; accL[uq][lane][1] = acc[1];
            accL[uq][lane][2] = acc[2]; accL[uq][lane][3] = acc[3];
            accL[uq][lane][4] = acc[6]; accL[uq][lane][5] = acc[7];
        }
        __syncthreads();
        if (kw == 0) {
            float rr0 = 1.f / (1.f + expf(-(acc[0] + accL[uq][lane][0] + bb0.x)));
            float rr1 = 1.f / (1.f + expf(-(acc[1] + accL[uq][lane][1] + bb1.x)));
            float zz0 = 1.f / (1.f + expf(-(acc[2] + accL[uq][lane][2] + bb0.y)));
            float zz1 = 1.f / (1.f + expf(-(acc[3] + accL[uq][lane][3] + bb1.y)));
            float hn0 = acc[6] + accL[uq][lane][4] + bb0.w;
            float hn1 = acc[7] + accL[uq][lane][5] + bb1.w;
            float nn0 = tanhf(acc[4] + bb0.z + rr0 * hn0);
            float nn1 = tanhf(acc[5] + bb1.z + rr1 * hn1);
            stf(&hout[(size_t)u0 * B_ + b], (1.f - zz0) * nn0 + zz0 * hold0);
            stf(&hout[(size_t)u1 * B_ + b], (1.f - zz1) * nn1 + zz1 * hold1);
        }
        asm volatile("s_waitcnt vmcnt(0)" ::: "memory");
        __syncthreads();
        if (tid == 0)
            __hip_atomic_store(&eflags[bid * 32], t + 1,
                               __ATOMIC_RELAXED, __HIP_MEMORY_SCOPE_AGENT);
    }
}

// ---------------------------------------------------------------------------
// PERSISTENT decoder. bid = bt*64 + jb. 2 phases/step, group-64 barriers.
// Phase 1: GRU. hin = ring[st] (cached, virgin slice); x gathered from
// read-only x via pred (sc1 scalar). hout = ring[st+1] (st<127) else hLast,
// published via sc1. Phase 2: block bb=bid: h column via sc1 (1 load/thread),
// hw2 in-block (w2q cached), scores vs proj (cached), softmax/argmax/loss,
// publish pred (sc1). Epochs: 2st+1 (h), 2st+2 (pred).
// ---------------------------------------------------------------------------
__global__ __launch_bounds__(512)
void dec_persist(const float* __restrict__ x,       // [B][S][F]
                 const int*   __restrict__ y,       // [B][C]
                 const float* __restrict__ W6,      // [256][640][6]
                 const float* __restrict__ bias4,   // [512][4]
                 const float4* __restrict__ w2q,    // [128 k4][512 a]
                 const float* __restrict__ v,       // [A]
                 const float* __restrict__ proj,    // [B][S][A]
                 float* __restrict__ ring,          // [128][H][B] (slice 0 = h_init)
                 float* __restrict__ hLast,         // [H][B]
                 int* __restrict__ predRing,        // [C][B]
                 float* __restrict__ nlogp, float* __restrict__ preds,
                 int* __restrict__ dflags)          // [256*32]
{
    __shared__ float accL[4][64][6];
    __shared__ float sh[512];
    __shared__ float sq[512];
    __shared__ float sScore[S_], sProb[S_];

    const int tid = threadIdx.x;
    const int lane = tid & 63;
    const int w = tid >> 6;
    const int kw = w >> 2;
    const int uq = w & 3;
    const int bid = blockIdx.x;
    const int bt = bid >> 6;
    const int gbase = bt * 64;
    const int b = bt * 64 + lane;
    const int up = (bid & 63) * 4 + uq;
    const float* Wb = W6 + (size_t)up * 3840;
    const int u0 = up * 2, u1 = u0 + 1;
    const float4 bb0 = *(const float4*)(bias4 + u0 * 4);
    const float4 bb1 = *(const float4*)(bias4 + u1 * 4);
    const float4 v0r = *(const float4*)(v + lane * 8);
    const float4 v1r = *(const float4*)(v + lane * 8 + 4);

    for (int st = 0; st < C_; ++st) {
        // ring[st] (h) and predRing[st] ready when group epoch >= 2*st
        if (st > 0) { group_wait(dflags, gbase, tid, 2 * st); }
        __syncthreads();

        const float* hin = ring + (size_t)st * HSLICE;
        float* hout = (st < C_ - 1) ? ring + (size_t)(st + 1) * HSLICE : hLast;

        // ---------------- phase 1: GRU ----------------
        {
            float acc[8];
#pragma unroll
            for (int g = 0; g < 8; ++g) acc[g] = 0.f;

            float hold0 = 0.f, hold1 = 0.f;
            if (kw == 0) {
                hold0 = hin[(size_t)u0 * B_ + b];
                hold1 = hin[(size_t)u1 * B_ + b];
                if (st > 0) {
                    int pb = __hip_atomic_load(&predRing[(st - 1) * B_ + b],
                                               __ATOMIC_RELAXED,
                                               __HIP_MEMORY_SCOPE_AGENT);
                    const float4* xr =
                        (const float4*)(x + ((size_t)b * S_ + pb) * F_);
                    acc_xrow(xr, Wb, acc);
                }
                acc_chunks<6>(hin, Wb + F_ * 6, 192, b, acc);
            } else {
                acc_chunks<6>(hin + (size_t)192 * B_, Wb + 320 * 6, 320, b, acc);
            }

            if (kw == 1) {
                accL[uq][lane][0] = acc[0]; accL[uq][lane][1] = acc[1];
                accL[uq][lane][2] = acc[2]; accL[uq][lane][3] = acc[3];
                accL[uq][lane][4] = acc[6]; accL[uq][lane][5] = acc[7];
            }
            __syncthreads();
            if (kw == 0) {
                float rr0 = 1.f / (1.f + expf(-(acc[0] + accL[uq][lane][0] + bb0.x)));
                float rr1 = 1.f / (1.f + expf(-(acc[1] + accL[uq][lane][1] + bb1.x)));
                float zz0 = 1.f / (1.f + expf(-(acc[2] + accL[uq][lane][2] + bb0.y)));
                float zz1 = 1.f / (1.f + expf(-(acc[3] + accL[uq][lane][3] + bb1.y)));
                float hn0 = acc[6] + accL[uq][lane][4] + bb0.w;
                float hn1 = acc[7] + accL[uq][lane][5] + bb1.w;
                float nn0 = tanhf(acc[4] + bb0.z + rr0 * hn0);
                float nn1 = tanhf(acc[5] + bb1.z + rr1 * hn1);
                stf(&hout[(size_t)u0 * B_ + b], (1.f - zz0) * nn0 + zz0 * hold0);
                stf(&hout[(size_t)u1 * B_ + b], (1.f - zz1) * nn1 + zz1 * hold1);
            }
            asm volatile("s_waitcnt vmcnt(0)" ::: "memory");
            __syncthreads();
            if (tid == 0)
                __hip_atomic_store(&dflags[bid * 32], 2 * st + 1,
                                   __ATOMIC_RELAXED, __HIP_MEMORY_SCOPE_AGENT);
        }

        // wait for whole group's h publish
        group_wait(dflags, gbase, tid, 2 * st + 1);
        __syncthreads();

        // ---------------- phase 2: attention (block = batch bb) ----------------
        {
            const int bb = bid;
            sh[tid] = ldf_sc(&hout[(size_t)tid * B_ + bb]);   // 1 sc1 load/thread
            __syncthreads();

            // hw2[bb][a], a = tid (w2q cached, coalesced)
            {
                float accw = 0.f;
                const float4* sh4 = (const float4*)sh;
#pragma unroll 8
                for (int k4 = 0; k4 < 128; ++k4)
                    accw += DOT4(sh4[k4], w2q[(size_t)k4 * 512 + tid]);
                sq[tid] = accw;
            }
            __syncthreads();

            float4 q0 = *(const float4*)&sq[lane * 8];
            float4 q1 = *(const float4*)&sq[lane * 8 + 4];
            const float* epb = proj + (size_t)bb * (S_ * A_);
            for (int si = 0; si < 16; ++si) {
                int ss = si * 8 + w;
                const float* row = epb + (size_t)ss * A_ + lane * 8;
                float4 p0 = *(const float4*)(row);
                float4 p1 = *(const float4*)(row + 4);
                float acc = fmaxf(p0.x + q0.x, 0.f) * v0r.x
                          + fmaxf(p0.y + q0.y, 0.f) * v0r.y
                          + fmaxf(p0.z + q0.z, 0.f) * v0r.z
                          + fmaxf(p0.w + q0.w, 0.f) * v0r.w
                          + fmaxf(p1.x + q1.x, 0.f) * v1r.x
                          + fmaxf(p1.y + q1.y, 0.f) * v1r.y
                          + fmaxf(p1.z + q1.z, 0.f) * v1r.z
                          + fmaxf(p1.w + q1.w, 0.f) * v1r.w;
#pragma unroll
                for (int off = 32; off; off >>= 1) acc += __shfl_down(acc, off);
                if (lane == 0) sScore[ss] = acc;
            }
            __syncthreads();

            if (tid < 64) {
                float s0v = sScore[tid], s1v = sScore[tid + 64];
                float m = fmaxf(s0v, s1v);
#pragma unroll
                for (int off = 32; off; off >>= 1) m = fmaxf(m, __shfl_xor(m, off));
                float e0 = expf(s0v - m), e1 = expf(s1v - m);
                float se = e0 + e1;
#pragma unroll
                for (int off = 32; off; off >>= 1) se += __shfl_xor(se, off);
                float p0 = e0 / se, p1 = e1 / se;
                sProb[tid] = p0; sProb[tid + 64] = p1;
                float pm = fmaxf(p0, p1);
#pragma unroll
                for (int off = 32; off; off >>= 1) pm = fmaxf(pm, __shfl_xor(pm, off));
                float t0 = expf(p0 - pm), t1 = expf(p1 - pm);
                float T = t0 + t1;
#pragma unroll
                for (int off = 32; off; off >>= 1) T += __shfl_xor(T, off);
                float bv = p0; int bi2 = tid;
                if (p1 > bv) { bv = p1; bi2 = tid + 64; }
#pragma unroll
                for (int off = 32; off; off >>= 1) {
                    float ov = __shfl_xor(bv, off);
                    int oi = __shfl_xor(bi2, off);
                    if (ov > bv || (ov == bv && oi < bi2)) { bv = ov; bi2 = oi; }
                }
                if (tid == 0) {
                    int yy = y[(size_t)bb * C_ + st];
                    float py = sProb[yy];
                    nlogp[(size_t)st * B_ + bb] = -(py - pm - logf(T));
                    preds[(size_t)bb * C_ + st] = (float)bi2;
                    __hip_atomic_store(&predRing[st * B_ + bb], bi2,
                                       __ATOMIC_RELAXED, __HIP_MEMORY_SCOPE_AGENT);
                }
            }
            asm volatile("s_waitcnt vmcnt(0)" ::: "memory");
            __syncthreads();
            if (tid == 0)
                __hip_atomic_store(&dflags[bid * 32], 2 * st + 2,
                                   __ATOMIC_RELAXED, __HIP_MEMORY_SCOPE_AGENT);
        }
    }
}

// ---------------------------------------------------------------------------
// proj[b][s][a] = sum_j encT[s][j][b] * w1[a][j]
// ---------------------------------------------------------------------------
__global__ __launch_bounds__(256)
void proj_gemm(const float* __restrict__ encT, const float* __restrict__ w1,
               float* __restrict__ proj)
{
    __shared__ float sA[32][128];
    __shared__ float sB[32][128];
    const int tid = threadIdx.x;
    const int s = blockIdx.z;
    const int b0 = blockIdx.y * 128;
    const int a0 = blockIdx.x * 128;
    const int tx = tid & 15, ty = tid >> 4;

    float acc[8][8];
#pragma unroll
    for (int i = 0; i < 8; ++i)
#pragma unroll
        for (int j = 0; j < 8; ++j) acc[i][j] = 0.f;

    const float* Abase = encT + (size_t)s * HSLICE + b0;
    for (int kc = 0; kc < H_; kc += 32) {
#pragma unroll
        for (int p = 0; p < 16; ++p) {
            int idx = tid + p * 256;
            int kj = idx >> 7, bbb = idx & 127;
            sA[kj][bbb] = Abase[(size_t)(kc + kj) * B_ + bbb];
        }
#pragma unroll
        for (int p = 0; p < 16; ++p) {
            int idx = tid + p * 256;
            int aa = idx >> 5, kj = idx & 31;
            sB[kj][aa] = w1[(size_t)(a0 + aa) * H_ + kc + kj];
        }
        __syncthreads();
#pragma unroll
        for (int kj = 0; kj < 32; ++kj) {
            float4 af0 = *(const float4*)&sA[kj][ty * 8];
            float4 af1 = *(const float4*)&sA[kj][ty * 8 + 4];
            float4 bf0 = *(const float4*)&sB[kj][tx * 8];
            float4 bf1 = *(const float4*)&sB[kj][tx * 8 + 4];
            float am[8] = {af0.x, af0.y, af0.z, af0.w, af1.x, af1.y, af1.z, af1.w};
            float bn[8] = {bf0.x, bf0.y, bf0.z, bf0.w, bf1.x, bf1.y, bf1.z, bf1.w};
#pragma unroll
            for (int i = 0; i < 8; ++i)
#pragma unroll
                for (int j = 0; j < 8; ++j)
                    acc[i][j] = fmaf(am[i], bn[j], acc[i][j]);
        }
        __syncthreads();
    }
#pragma unroll
    for (int i = 0; i < 8; ++i) {
        float* dst = proj + ((size_t)(b0 + ty * 8 + i) * S_ + s) * A_ + a0 + tx * 8;
        *(float4*)(dst) = make_float4(acc[i][0], acc[i][1], acc[i][2], acc[i][3]);
        *(float4*)(dst + 4) = make_float4(acc[i][4], acc[i][5], acc[i][6], acc[i][7]);
    }
}

__global__ void final_loss(const float* __restrict__ nlogp, float* __restrict__ out)
{
    __shared__ float part[C_];
    const int i = threadIdx.x; // 128
    float s = 0.f;
    for (int b = 0; b < B_; ++b) s += nlogp[(size_t)i * B_ + b];
    part[i] = s / (float)B_;
    __syncthreads();
    if (i == 0) {
        float t = 0.f;
        for (int k = 0; k < C_; ++k) t += part[k];
        out[0] = t / (float)B_ / (float)C_;
    }
}

extern "C" void kernel_launch(void* const* d_in, const int* in_sizes, int n_in,
                              void* d_out, int out_size, void* d_ws, size_t ws_size,
                              hipStream_t stream)
{
    (void)in_sizes; (void)n_in; (void)out_size; (void)ws_size;
    const float* x    = (const float*)d_in[0];
    const int*   y    = (const int*)d_in[1];
    const float* eWih = (const float*)d_in[2];
    const float* eWhh = (const float*)d_in[3];
    const float* ebih = (const float*)d_in[4];
    const float* ebhh = (const float*)d_in[5];
    const float* dWih = (const float*)d_in[6];
    const float* dWhh = (const float*)d_in[7];
    const float* dbih = (const float*)d_in[8];
    const float* dbhh = (const float*)d_in[9];
    const float* w1   = (const float*)d_in[10];
    const float* w2   = (const float*)d_in[11];
    const float* v    = (const float*)d_in[12];
    float* out = (float*)d_out;

    float* ws = (float*)d_ws;
    // Region A [0, 16,777,216): encT during encode; h-ring[128] during decode.
    float* encT   = ws;
    float* ring   = ws;
    float* encT127 = ws + (size_t)127 * HSLICE;
    // Region B [16,777,216, 33,554,432): proj. Pre-proj: xT, W6e, h0T.
    float* projB  = ws + 16777216;
    float* xT     = projB;                    // 4,194,304
    float* W6e    = projB + 4194304;          // 983,040
    float* h0T    = projB + 5177344;          // 131,072
    // Region C beyond 33,554,432:
    float* C0     = ws + 33554432;
    float* bias4e = C0;                       // 2048
    float* bias4d = C0 + 2048;                // 2048
    float* nlogp  = C0 + 4096;                // 32,768
    float* hLast  = C0 + 36864;               // 131,072
    float* w2qf   = C0 + 167936;              // 262,144
    float* W6d    = C0 + 430080;              // 983,040
    int*   eflags   = (int*)(C0 + 1413120);   // 8192 ints
    int*   dflags   = eflags + 8192;          // 8192 ints
    int*   predRing = dflags + 8192;          // 32,768 ints

    // ---- prep ----
    prep_bias<<<dim3(512), 256, 0, stream>>>(ebih, ebhh, dbih, dbhh,
                                             bias4e, bias4d, h0T, eflags, dflags);
    transpose_x<<<dim3(512), 256, 0, stream>>>(x, xT);
    prep_w6<<<dim3(3840), 256, 0, stream>>>(eWih, eWhh, W6e,
                                            (const float*)nullptr,
                                            (float*)nullptr, 0);

    // ---- encoder: ONE persistent kernel ----
    {
        void* a[] = { (void*)&xT, (void*)&W6e, (void*)&bias4e, (void*)&h0T,
                      (void*)&encT, (void*)&eflags };
        hipLaunchCooperativeKernel((const void*)enc_persist,
                                   dim3(256), dim3(512), a, 0, stream);
    }

    // ---- proj (reads all encT) ----
    proj_gemm<<<dim3(4, 2, 128), 256, 0, stream>>>(encT, w1, projB);

    // ---- decoder prep: W6d (region C) + copy h_init -> ring[0]; w2q ----
    prep_w6<<<dim3(3840), 256, 0, stream>>>(dWih, dWhh, W6d,
                                            encT127, ring, HSLICE);
    prep_w2q<<<dim3(256), 256, 0, stream>>>(w2, (float4*)w2qf);

    // ---- decoder: ONE persistent kernel ----
    {
        void* a[] = { (void*)&x, (void*)&y, (void*)&W6d, (void*)&bias4d,
                      (void*)&w2qf, (void*)&v, (void*)&projB, (void*)&ring,
                      (void*)&hLast, (void*)&predRing, (void*)&nlogp,
                      (void*)&out, (void*)&dflags };
        hipLaunchCooperativeKernel((const void*)dec_persist,
                                   dim3(256), dim3(512), a, 0, stream);
    }

    final_loss<<<dim3(1), 128, 0, stream>>>(nlogp, out + (size_t)B_ * C_);
}